// Round 8
// baseline (101.285 us; speedup 1.0000x reference)
//
#include <hip/hip_runtime.h>

typedef __attribute__((ext_vector_type(4))) float f32x4;
typedef __attribute__((ext_vector_type(8))) short bf16x8;
typedef __attribute__((ext_vector_type(4))) unsigned int u32x4;

#define IDIM    128
#define HID     64
#define TDEPTH  6
#define WROWS   32                       // rows per wave
#define NWAVES  8
#define BLOCK   (NWAVES * 64)            // 512
#define MROWS   (WROWS * NWAVES)         // 256 rows per block
#define NODE_ELEMS 8192                  // shorts per node B-fragment slice (16 KB)
#define WFRAG_ELEMS (TDEPTH * NODE_ELEMS)

__device__ __forceinline__ unsigned short f2bf(float f) {
    unsigned int u = __builtin_bit_cast(unsigned int, f);
    unsigned int r = (u + 0x7FFFu + ((u >> 16) & 1u)) >> 16;  // RNE
    return (unsigned short)r;
}

__device__ __forceinline__ unsigned int f2bf_pk(float f0, float f1) {
    unsigned int u0 = __builtin_bit_cast(unsigned int, f0);
    unsigned int u1 = __builtin_bit_cast(unsigned int, f1);
    unsigned int t0 = u0 + 0x7FFFu + ((u0 >> 16) & 1u);
    unsigned int t1 = u1 + 0x7FFFu + ((u1 >> 16) & 1u);
    return (t1 & 0xFFFF0000u) | (t0 >> 16);
}

// Pre-convert W1 (6 chain nodes) into bf16 MFMA B-fragment layout, node-major.
// B-frag: lane holds B[k=(lane>>4)*8+j][n=lane&15]. Workspace use is free (the
// harness's 268 MB poison fill runs unconditionally and evicts L3 every iter).
__global__ void prep_wfrag(const float* __restrict__ W1, unsigned short* __restrict__ wfrag) {
    int idx = blockIdx.x * 256 + threadIdx.x;
    if (idx >= WFRAG_ELEMS) return;
    int j    = idx & 7;
    int lane = (idx >> 3) & 63;
    int ct   = (idx >> 9) & 3;
    int ks   = (idx >> 11) & 3;
    int nd   = idx >> 13;
    int node = (1 << nd) - 1;              // chain node: 0,1,3,7,15,31
    int k    = ks * 32 + (lane >> 4) * 8 + j;
    int col  = ct * 16 + (lane & 15);
    wfrag[idx] = f2bf(W1[(node * IDIM + k) * HID + col]);
}

// Round-8 structure: R7's A-path (one 16-dwordx4 burst per wave, held in regs)
// + ZERO barriers in the node loop. 8 waves x 32 rows = 256 rows/block, grid
// 256 = 1 block/CU (LDS ~63 KB -> capacity 2, absorbs dispatch imbalance).
// B staged in two 3-node halves (48 KB LDS), each staged once, never rewritten
// -> waves run 3 nodes fully independently between barriers (4 barriers total
// vs R7's 7 per-node drains). b1/W2/b2/leaf staged to LDS once -> no global
// loads in the node loop. #pragma unroll 1 on nd caps register pressure
// (rounds 1/4/5 spill lesson); launch_bounds(512,2) -> 256-reg cap, no spill.
template <bool USE_WS>
__global__ __launch_bounds__(BLOCK, 2)
void sdt_kernel(const float* __restrict__ x, const float* __restrict__ W1,
                const float* __restrict__ b1, const float* __restrict__ W2,
                const float* __restrict__ b2, const float* __restrict__ leaf,
                const unsigned short* __restrict__ wfrag, float* __restrict__ out) {
    __shared__ __align__(16) unsigned short bs[3 * NODE_ELEMS];  // 48 KB: 3 nodes
    __shared__ float p_lds[NWAVES][WROWS][9];                    // stride 9: conflict-light
    __shared__ float b1s[TDEPTH][HID];
    __shared__ float w2s[TDEPTH][HID];
    __shared__ float b2s[8];
    __shared__ float leaf_lds[64];

    const int tid  = threadIdx.x;
    const int wave = tid >> 6;
    const int lane = tid & 63;
    const int lcol = lane & 15;
    const int lq   = lane >> 4;
    const int m0   = blockIdx.x * MROWS + wave * WROWS;

    // ---- A: this wave's 32 rows, straight from HBM, one burst (starts the
    // x stream chip-wide at cycle 0) ----
    // A-frag target: lane holds A[row = rt*16 + lcol][k = ks*32 + lq*8 + j]
    const float* xb = x + (size_t)(m0 + lcol) * IDIM + lq * 8;
    float4 araw[2][4][2];
    #pragma unroll
    for (int rt = 0; rt < 2; rt++)
        #pragma unroll
        for (int ks = 0; ks < 4; ks++) {
            const float4* ap = reinterpret_cast<const float4*>(
                xb + (size_t)(rt * 16) * IDIM + ks * 32);
            araw[rt][ks][0] = ap[0];
            araw[rt][ks][1] = ap[1];
        }

    // ---- cooperative stage of nodes [nd0, nd0+3) into bs ----
    auto stage3 = [&](int nd0) {
        if (USE_WS) {
            const u32x4* src = reinterpret_cast<const u32x4*>(
                wfrag + (size_t)nd0 * NODE_ELEMS);
            u32x4* dst = reinterpret_cast<u32x4*>(&bs[0]);
            #pragma unroll
            for (int i = 0; i < 6; i++)              // 3*16KB / 16B / 512
                dst[tid + i * BLOCK] = src[tid + i * BLOCK];
        } else {
            for (int e = tid; e < 3 * NODE_ELEMS; e += BLOCK) {
                int j = e & 7, ln = (e >> 3) & 63, ct = (e >> 9) & 3,
                    ks = (e >> 11) & 3, ndl = e >> 13;
                int node = (1 << (nd0 + ndl)) - 1;
                int k    = ks * 32 + (ln >> 4) * 8 + j;
                int col  = ct * 16 + (ln & 15);
                bs[e] = f2bf(W1[((size_t)node * IDIM + k) * HID + col]);
            }
        }
    };

    stage3(0);
    // ---- stage epilogue params + leaf once ----
    if (tid < 384) {
        int nd = tid >> 6, col = tid & 63, node = (1 << nd) - 1;
        b1s[nd][col] = b1[node * HID + col];
        w2s[nd][col] = W2[node * HID + col];
    }
    if (tid < 6)  b2s[tid] = b2[(1 << tid) - 1];
    if (tid < 64) leaf_lds[tid] = leaf[tid];

    // ---- convert A to bf16 fragments (held for all 6 nodes) ----
    bf16x8 afrag[2][4];
    #pragma unroll
    for (int rt = 0; rt < 2; rt++)
        #pragma unroll
        for (int ks = 0; ks < 4; ks++) {
            float4 v0 = araw[rt][ks][0], v1 = araw[rt][ks][1];
            u32x4 pk;
            pk[0] = f2bf_pk(v0.x, v0.y);
            pk[1] = f2bf_pk(v0.z, v0.w);
            pk[2] = f2bf_pk(v1.x, v1.y);
            pk[3] = f2bf_pk(v1.z, v1.w);
            afrag[rt][ks] = __builtin_bit_cast(bf16x8, pk);
        }

    __syncthreads();                       // bar1: bs(0..2) + params ready

    auto compute = [&](int nd, int ndl) {
        // ---- GEMM: 32 rows x 64 cols, K=128; B from LDS ----
        f32x4 acc[2][4];
        #pragma unroll
        for (int rt = 0; rt < 2; rt++)
            #pragma unroll
            for (int ct = 0; ct < 4; ct++)
                acc[rt][ct] = (f32x4){0.f, 0.f, 0.f, 0.f};
        #pragma unroll
        for (int ks = 0; ks < 4; ks++) {
            bf16x8 bfrag[4];
            #pragma unroll
            for (int ct = 0; ct < 4; ct++)
                bfrag[ct] = *reinterpret_cast<const bf16x8*>(
                    &bs[ndl * NODE_ELEMS + (ks * 4 + ct) * 512 + lane * 8]);
            #pragma unroll
            for (int rt = 0; rt < 2; rt++)
                #pragma unroll
                for (int ct = 0; ct < 4; ct++)
                    acc[rt][ct] = __builtin_amdgcn_mfma_f32_16x16x32_bf16(
                        afrag[rt][ks], bfrag[ct], acc[rt][ct], 0, 0, 0);
        }

        // ---- epilogue: relu, dot W2, sigmoid -> p_lds ----
        // C layout: col = ct*16 + lcol, row = rt*16 + lq*4 + r
        float b1v[4], w2v[4];
        #pragma unroll
        for (int ct = 0; ct < 4; ct++) {
            b1v[ct] = b1s[nd][ct * 16 + lcol];
            w2v[ct] = w2s[nd][ct * 16 + lcol];
        }
        const float bias2 = b2s[nd];
        #pragma unroll
        for (int rt = 0; rt < 2; rt++) {
            #pragma unroll
            for (int r = 0; r < 4; r++) {
                float s = 0.f;
                #pragma unroll
                for (int ct = 0; ct < 4; ct++) {
                    float v = acc[rt][ct][r] + b1v[ct];
                    v = v > 0.f ? v : 0.f;
                    s += v * w2v[ct];
                }
                #pragma unroll
                for (int d = 1; d < 16; d <<= 1)
                    s += __shfl_xor(s, d, 64);
                float p = 1.f / (1.f + __expf(-(s + bias2)));
                if (lcol == 0)
                    p_lds[wave][rt * 16 + lq * 4 + r][nd] = p;
            }
        }
    };

    #pragma unroll 1
    for (int nd = 0; nd < 3; nd++) compute(nd, nd);
    __syncthreads();                       // bar2: all waves done reading bs
    stage3(3);
    __syncthreads();                       // bar3: bs(3..5) ready
    #pragma unroll 1
    for (int nd = 3; nd < 6; nd++) compute(nd, nd - 3);
    __syncthreads();                       // bar4: p_lds complete

    // ---- fold: 256 threads, one per row ----
    if (tid < MROWS) {
        const int wv = tid >> 5, row = tid & 31;
        float q0 = p_lds[wv][row][0];
        float q1 = p_lds[wv][row][1];
        float q2 = p_lds[wv][row][2];
        float q3 = p_lds[wv][row][3];
        float p4 = p_lds[wv][row][4];
        float p5 = p_lds[wv][row][5];
        float acc_out = 0.f;
        #pragma unroll
        for (int ch = 0; ch < 4; ch++) {
            float f4 = (ch & 1) ? p4 : 1.f - p4;
            float f5 = (ch & 2) ? p5 : 1.f - p5;
            const float* lf = leaf_lds + ch * 16;
            float tt[8];
            #pragma unroll
            for (int j = 0; j < 8; j++) {
                float a = lf[2 * j], b = lf[2 * j + 1];
                tt[j] = a + q0 * (b - a);
            }
            #pragma unroll
            for (int j = 0; j < 4; j++) tt[j] = tt[2 * j] + q1 * (tt[2 * j + 1] - tt[2 * j]);
            #pragma unroll
            for (int j = 0; j < 2; j++) tt[j] = tt[2 * j] + q2 * (tt[2 * j + 1] - tt[2 * j]);
            float s = tt[0] + q3 * (tt[1] - tt[0]);
            acc_out += f4 * f5 * s;
        }
        out[(size_t)blockIdx.x * MROWS + tid] = acc_out;
    }
}

extern "C" void kernel_launch(void* const* d_in, const int* in_sizes, int n_in,
                              void* d_out, int out_size, void* d_ws, size_t ws_size,
                              hipStream_t stream) {
    const float* x    = (const float*)d_in[0];
    const float* W1   = (const float*)d_in[1];
    const float* b1   = (const float*)d_in[2];
    const float* W2   = (const float*)d_in[3];
    const float* b2   = (const float*)d_in[4];
    const float* leaf = (const float*)d_in[5];
    float* out = (float*)d_out;

    const int Bn = in_sizes[0] / IDIM;               // 65536 rows
    const int nblocks = Bn / MROWS;                  // 256 — 1 block/CU

    if (ws_size >= (size_t)WFRAG_ELEMS * sizeof(unsigned short)) {
        unsigned short* wfrag = (unsigned short*)d_ws;
        prep_wfrag<<<(WFRAG_ELEMS + 255) / 256, 256, 0, stream>>>(W1, wfrag);
        sdt_kernel<true><<<nblocks, BLOCK, 0, stream>>>(x, W1, b1, W2, b2, leaf, wfrag, out);
    } else {
        sdt_kernel<false><<<nblocks, BLOCK, 0, stream>>>(x, W1, b1, W2, b2, leaf, nullptr, out);
    }
}